// Round 5
// baseline (470.776 us; speedup 1.0000x reference)
//
#include <hip/hip_runtime.h>
#include <math.h>

#define N_NODES 50000
#define N_EDGES 1600000
#define F_IN    256
#define DIMS    64
#define N_CLS   16
#define R_REL   8
#define CAP     96          // per-destination CSR capacity (in-deg ~Poisson(32))

#define BM      64          // proj tile rows
#define N_TILES 782         // ceil(50000/64)
#define N_GRP   5           // relation groups {0,1},{2,3},{4,5},{6,7},{8}
#define PROJ_BLKS (N_TILES * N_GRP)   // 3910
#define CSR_BLKS  3125      // 2 edges/thread: 3125*256*2 == N_EDGES
#define FRONT_BLKS (PROJ_BLKS + CSR_BLKS)   // 7035

typedef short bf16x8 __attribute__((ext_vector_type(8)));
typedef float f32x4  __attribute__((ext_vector_type(4)));
typedef unsigned int u32;
typedef const __attribute__((address_space(1))) u32* gas_ptr;
typedef __attribute__((address_space(3))) u32* las_ptr;

__device__ __forceinline__ void async16(const void* g, void* l) {
    // global->LDS DMA, 16B/lane; LDS dest = uniform base + lane*16
    __builtin_amdgcn_global_load_lds((gas_ptr)g, (las_ptr)l, 16, 0, 0);
}

__device__ __forceinline__ unsigned short f2bf(float f) {
    unsigned u = __float_as_uint(f);
    unsigned r = (u + 0x7fffu + ((u >> 16) & 1u)) >> 16;
    return (unsigned short)r;
}
__device__ __forceinline__ float bf2f(unsigned short u) {
    return __uint_as_float(((unsigned)u) << 16);
}

// ---------- convert x -> bf16 ----------
__global__ __launch_bounds__(256) void cvt_x_kernel(
        const float* __restrict__ x, ushort* __restrict__ xb) {
    int i4 = blockIdx.x * 256 + threadIdx.x;       // 3.2M quads
    float4 v = ((const float4*)x)[i4];
    ushort4 o;
    o.x = f2bf(v.x); o.y = f2bf(v.y); o.z = f2bf(v.z); o.w = f2bf(v.w);
    ((ushort4*)xb)[i4] = o;
}

// ---------- build wt1[r][n][k] bf16 (transposed, slot 8 = root1) ----------
__global__ __launch_bounds__(256) void cvt_w_kernel(
        const float* __restrict__ W1, const float* __restrict__ root1,
        ushort* __restrict__ wt1) {
    int idx = blockIdx.x * 256 + threadIdx.x;      // 9*64*256 = 147456
    int r = idx >> 14, rem = idx & 16383;
    int n = rem >> 8, k = rem & 255;
    float v = (r < 8) ? W1[((size_t)r * F_IN + k) * DIMS + n]
                      : root1[(size_t)k * DIMS + n];
    wt1[idx] = f2bf(v);
}

// ---------- fused front: proj1 MFMA (+si/sj, +x@root1) AND CSR build ----------
// v6: BM=64 tiles x 5 relation-groups (2 rels share one staged tile) =
// 3910 proj blocks -- keeps the round-0 wave count (the verified
// parallelism requirement) while cutting xb staging 9x -> 5x (~45 MB less
// HBM fetch; front measured BW-bound at ~2 TB/s blended).
// CSR branch: round-3 verified optimum (2 edges/thread, 3125 blocks).
__global__ __launch_bounds__(256, 6) void front_kernel(
        const ushort* __restrict__ xb, const ushort* __restrict__ wt1,
        const float* __restrict__ at1,
        ushort* __restrict__ xr1b, float* __restrict__ hroot,
        float* __restrict__ si1, float* __restrict__ sj1,
        const int* __restrict__ ei, const int* __restrict__ ecol,
        const float* __restrict__ ew, int* __restrict__ fill,
        unsigned long long* __restrict__ rec) {
    __shared__ ushort xs[BM * 64];                 // 8 KB, swizzled [row][k8^(row&7)]
    const int bid = blockIdx.x;
    const int t = threadIdx.x;

    // interleave: proj/CSR alternate for the first 2*CSR_BLKS bids, then
    // the remaining proj blocks (tail = root-slot projections, MFMA-heavy)
    int pb = -1, cb = -1;
    if (bid < 2 * CSR_BLKS) { if (bid & 1) cb = bid >> 1; else pb = bid >> 1; }
    else pb = CSR_BLKS + (bid - 2 * CSR_BLKS);

    if (cb >= 0) {
        // ----- CSR build branch: 2 edges/thread, independent chains -----
        int idx = cb * 256 + t;                    // edge-pair index
        int2  s2 = ((const int2*)ei)[idx];
        int2  d2 = ((const int2*)(ei + N_EDGES))[idx];
        int2  c2 = ((const int2*)ecol)[idx];
        float2 w2 = ((const float2*)ew)[idx];
        int p0 = atomicAdd(&fill[d2.x], 1);
        int p1 = atomicAdd(&fill[d2.y], 1);
        unsigned long long r0 =
            ((unsigned long long)__float_as_uint(w2.x) << 32)
            | (unsigned)(s2.x | (c2.x << 16));
        unsigned long long r1 =
            ((unsigned long long)__float_as_uint(w2.y) << 32)
            | (unsigned)(s2.y | (c2.y << 16));
        int i0 = (p0 < CAP) ? d2.x * CAP + p0 : N_NODES * CAP;   // overflow dump
        int i1 = (p1 < CAP) ? d2.y * CAP + p1 : N_NODES * CAP;
        __builtin_nontemporal_store(r0, &rec[i0]);
        __builtin_nontemporal_store(r1, &rec[i1]);
        return;
    }

    // ----- proj1 MFMA branch: one 64-row tile, 2 relations per block -----
    const int g = pb / N_TILES;                    // relation group 0..4
    const int node0 = (pb % N_TILES) * BM;
    const int r0g = g * 2;                         // first relation of group
    const int nrel = (g < 4) ? 2 : 1;              // group 4 = {root}

    const int w = t >> 6, lane = t & 63;
    const int lane15 = lane & 15, quad = lane >> 4;
    const int row0 = w * 16 + lane15;              // wave strip: rows w*16..+15
    const int sw0 = row0 & 7;

    f32x4 acc[2][4];
    #pragma unroll
    for (int a = 0; a < 2; ++a)
        #pragma unroll
        for (int b = 0; b < 4; ++b)
            acc[a][b] = (f32x4){0.f, 0.f, 0.f, 0.f};

    for (int s = 0; s < 4; ++s) {                  // K staged 4 x 64
        __syncthreads();
        #pragma unroll
        for (int c = 0; c < 2; ++c) {              // 2 x 256 lane-slots of 16B
            int slot = c * 256 + t;
            int row = slot >> 3, k8p = slot & 7;
            int k8 = k8p ^ (row & 7);              // source-side swizzle
            int node = node0 + row;
            if (node >= N_NODES) node = N_NODES - 1;   // clamp (garbage ok, rows discarded)
            async16(&xb[(size_t)node * 256 + s * 64 + k8 * 8],
                    &xs[(c * 256 + w * 64) * 8]);
        }
        __syncthreads();                           // drains vmcnt incl. lds-DMA
        #pragma unroll
        for (int kk = 0; kk < 2; ++kk) {
            int k8 = kk * 4 + quad;
            int aidx = row0 * 64 + ((k8 ^ sw0) << 3);
            bf16x8 a0 = *(const bf16x8*)&xs[aidx];
            int kg = s * 64 + kk * 32 + quad * 8;
            #pragma unroll
            for (int ri = 0; ri < 2; ++ri) {
                if (ri < nrel) {
                    const ushort* wrow = wt1 + (size_t)(r0g + ri) * 64 * 256;
                    #pragma unroll
                    for (int nt = 0; nt < 4; ++nt) {
                        bf16x8 b = *(const bf16x8*)&wrow[(size_t)(nt * 16 + lane15) * 256 + kg];
                        acc[ri][nt] = __builtin_amdgcn_mfma_f32_16x16x32_bf16(a0, b, acc[ri][nt], 0, 0, 0);
                    }
                }
            }
        }
    }

    #pragma unroll
    for (int ri = 0; ri < 2; ++ri) {
        if (ri >= nrel) break;
        const int r = r0g + ri;
        const float* at = at1 + r * 128;
        float pi[4] = {0.f, 0.f, 0.f, 0.f};
        float pj[4] = {0.f, 0.f, 0.f, 0.f};
        #pragma unroll
        for (int nt = 0; nt < 4; ++nt) {
            int gcol = nt * 16 + lane15;
            float ai = 0.f, aj = 0.f;
            if (r < 8) { ai = at[gcol]; aj = at[64 + gcol]; }
            #pragma unroll
            for (int reg = 0; reg < 4; ++reg) {
                float v = acc[ri][nt][reg];
                int grow = node0 + w * 16 + quad * 4 + reg;
                if (grow < N_NODES) {
                    if (r < 8)
                        xr1b[((size_t)r * N_NODES + grow) * 64 + gcol] = f2bf(v);
                    else
                        hroot[(size_t)grow * 64 + gcol] = v;
                }
                pi[reg] += ai * v;
                pj[reg] += aj * v;
            }
        }
        if (r < 8) {
            #pragma unroll
            for (int reg = 0; reg < 4; ++reg) {
                float s_ = pi[reg], u_ = pj[reg];
                #pragma unroll
                for (int off = 1; off < 16; off <<= 1) {
                    s_ += __shfl_xor(s_, off, 64);
                    u_ += __shfl_xor(u_, off, 64);
                }
                if (lane15 == 0) {
                    int grow = node0 + w * 16 + quad * 4 + reg;
                    if (grow < N_NODES) {
                        si1[r * N_NODES + grow] = s_;
                        sj1[r * N_NODES + grow] = u_;
                    }
                }
            }
        }
    }
}

// ---------- layer 1: fused score + aggregate + finalize ----------
__global__ __launch_bounds__(256) void agg1s_kernel(
        const unsigned long long* __restrict__ rec, const int* __restrict__ fill,
        const float* __restrict__ si, const float* __restrict__ sj,
        const ushort* __restrict__ xr1b, const float* __restrict__ hroot,
        const float* __restrict__ bias1, float* __restrict__ h) {
    __shared__ int   esrc[4][CAP];
    __shared__ float ecoef[4][CAP];
    __shared__ float sden[4][8];
    __shared__ int   scnt[4][8];
    __shared__ float ssi[4][8];
    const int t = threadIdx.x;
    const int w = t >> 6, lane = t & 63;
    const int d = blockIdx.x * 4 + w;              // 12500*4 == N_NODES
    if (lane < 8) {
        sden[w][lane] = 0.f; scnt[w][lane] = 0;
        ssi[w][lane] = si[lane * N_NODES + d];
    }
    const int n = min(fill[d], CAP);
    const int base = d * CAP;
    float ex[2] = {0.f, 0.f}, ww[2] = {0.f, 0.f};
    int cc[2] = {0, 0};
    #pragma unroll
    for (int ii = 0; ii < 2; ++ii) {
        int i = lane + ii * 64;
        if (i < n) {
            unsigned long long rv = rec[base + i];
            int px = (int)(unsigned)rv;
            int s = px & 0xffff, c = (px >> 16) & 0x7fff;
            esrc[w][i] = px;
            float sc = ssi[w][c] + sj[c * N_NODES + s];
            sc = sc > 0.f ? sc : 0.2f * sc;
            float e = __expf(sc);
            ex[ii] = e; cc[ii] = c; ww[ii] = __uint_as_float((unsigned)(rv >> 32));
            atomicAdd(&sden[w][c], e);
            atomicAdd(&scnt[w][c], 1);
        }
    }
    #pragma unroll
    for (int ii = 0; ii < 2; ++ii) {
        int i = lane + ii * 64;
        if (i < n)
            ecoef[w][i] = ex[ii] / fmaxf(sden[w][cc[ii]], 1e-16f)
                          * ww[ii] / (float)scnt[w][cc[ii]];
    }
    // phase 2: 8-way unrolled gather (independent chains -> more MLP)
    float a0 = 0.f, a1 = 0.f, a2 = 0.f, a3 = 0.f;
    float a4 = 0.f, a5 = 0.f, a6 = 0.f, a7 = 0.f;
    int i = 0;
    for (; i + 8 <= n; i += 8) {
        int p0 = esrc[w][i],     p1 = esrc[w][i + 1];
        int p2 = esrc[w][i + 2], p3 = esrc[w][i + 3];
        int p4 = esrc[w][i + 4], p5 = esrc[w][i + 5];
        int p6 = esrc[w][i + 6], p7 = esrc[w][i + 7];
        float c0 = ecoef[w][i],     c1 = ecoef[w][i + 1];
        float c2 = ecoef[w][i + 2], c3 = ecoef[w][i + 3];
        float c4 = ecoef[w][i + 4], c5 = ecoef[w][i + 5];
        float c6 = ecoef[w][i + 6], c7 = ecoef[w][i + 7];
        int r0 = (p0 >> 16) * N_NODES + (p0 & 0xffff);
        int r1 = (p1 >> 16) * N_NODES + (p1 & 0xffff);
        int r2 = (p2 >> 16) * N_NODES + (p2 & 0xffff);
        int r3 = (p3 >> 16) * N_NODES + (p3 & 0xffff);
        int r4 = (p4 >> 16) * N_NODES + (p4 & 0xffff);
        int r5 = (p5 >> 16) * N_NODES + (p5 & 0xffff);
        int r6 = (p6 >> 16) * N_NODES + (p6 & 0xffff);
        int r7 = (p7 >> 16) * N_NODES + (p7 & 0xffff);
        a0 += c0 * bf2f(xr1b[(size_t)r0 * 64 + lane]);
        a1 += c1 * bf2f(xr1b[(size_t)r1 * 64 + lane]);
        a2 += c2 * bf2f(xr1b[(size_t)r2 * 64 + lane]);
        a3 += c3 * bf2f(xr1b[(size_t)r3 * 64 + lane]);
        a4 += c4 * bf2f(xr1b[(size_t)r4 * 64 + lane]);
        a5 += c5 * bf2f(xr1b[(size_t)r5 * 64 + lane]);
        a6 += c6 * bf2f(xr1b[(size_t)r6 * 64 + lane]);
        a7 += c7 * bf2f(xr1b[(size_t)r7 * 64 + lane]);
    }
    for (; i < n; ++i) {
        int p0 = esrc[w][i];
        int r0 = (p0 >> 16) * N_NODES + (p0 & 0xffff);
        a0 += ecoef[w][i] * bf2f(xr1b[(size_t)r0 * 64 + lane]);
    }
    float acc = ((a0 + a1) + (a2 + a3)) + ((a4 + a5) + (a6 + a7))
              + hroot[(size_t)d * 64 + lane] + bias1[lane];
    h[(size_t)d * 64 + lane] = fmaxf(acc, 0.f);
}

// ---------- layer 2 projection + si2/sj2 fused (bf16 xr2 out) ----------
__global__ __launch_bounds__(256) void proj2_kernel(
        const float* __restrict__ h, const float* __restrict__ W2,
        const float* __restrict__ atten2, ushort* __restrict__ xr2b,
        float* __restrict__ si2, float* __restrict__ sj2) {
    __shared__ float w2sh[8][64][16];   // 32 KB, [r][k][c]
    __shared__ float a2sh[8][32];
    __shared__ float hsh[32][65];
    const int t = threadIdx.x;
    for (int i = t; i < R_REL * DIMS * N_CLS; i += 256)
        w2sh[i >> 10][(i >> 4) & 63][i & 15] = W2[i];
    if (t < R_REL * 2 * N_CLS) a2sh[t >> 5][t & 31] = atten2[t];
    const int node0 = blockIdx.x * 32;
    for (int i = t; i < 32 * 64; i += 256) {
        int nn = i >> 6, kk = i & 63;
        int node = node0 + nn;
        hsh[nn][kk] = (node < N_NODES) ? h[(size_t)node * 64 + kk] : 0.f;
    }
    __syncthreads();
    const int nl = t & 31, r = t >> 5;
    const int node = node0 + nl;
    float acc[16] = {};
    #pragma unroll 4
    for (int k = 0; k < 64; ++k) {
        float hv = hsh[nl][k];
        #pragma unroll
        for (int c = 0; c < 16; ++c) acc[c] += hv * w2sh[r][k][c];
    }
    if (node < N_NODES) {
        float si = 0.f, sj = 0.f;
        size_t base = ((size_t)r * N_NODES + node) * 16;
        #pragma unroll
        for (int c = 0; c < 16; ++c) {
            si += a2sh[r][c] * acc[c];
            sj += a2sh[r][16 + c] * acc[c];
        }
        #pragma unroll
        for (int c4 = 0; c4 < 4; ++c4) {
            ushort4 o;
            o.x = f2bf(acc[c4 * 4 + 0]); o.y = f2bf(acc[c4 * 4 + 1]);
            o.z = f2bf(acc[c4 * 4 + 2]); o.w = f2bf(acc[c4 * 4 + 3]);
            *(ushort4*)&xr2b[base + c4 * 4] = o;
        }
        si2[r * N_NODES + node] = si;
        sj2[r * N_NODES + node] = sj;
    }
}

// ---------- layer 2: fused score + aggregate + root2 + log_softmax ----------
__global__ __launch_bounds__(256) void agg2s_kernel(
        const unsigned long long* __restrict__ rec, const int* __restrict__ fill,
        const float* __restrict__ si, const float* __restrict__ sj,
        const ushort* __restrict__ xr2b, const float* __restrict__ h,
        const float* __restrict__ root2, const float* __restrict__ bias2,
        float* __restrict__ out) {
    __shared__ float rsh[64][17];
    __shared__ float hsh[4][64];
    __shared__ int   esrc[4][CAP];
    __shared__ float ecoef[4][CAP];
    __shared__ float sden[4][8];
    __shared__ int   scnt[4][8];
    __shared__ float ssi[4][8];
    const int t = threadIdx.x;
    for (int i = t; i < DIMS * N_CLS; i += 256) rsh[i >> 4][i & 15] = root2[i];
    const int w = t >> 6, lane = t & 63;
    const int d = blockIdx.x * 4 + w;
    hsh[w][lane] = h[(size_t)d * 64 + lane];
    if (lane < 8) {
        sden[w][lane] = 0.f; scnt[w][lane] = 0;
        ssi[w][lane] = si[lane * N_NODES + d];
    }
    const int n = min(fill[d], CAP);
    const int base = d * CAP;
    float ex[2] = {0.f, 0.f}, ww[2] = {0.f, 0.f};
    int cc[2] = {0, 0};
    #pragma unroll
    for (int ii = 0; ii < 2; ++ii) {
        int i = lane + ii * 64;
        if (i < n) {
            unsigned long long rv = rec[base + i];
            int px = (int)(unsigned)rv;
            int s = px & 0xffff, c = (px >> 16) & 0x7fff;
            esrc[w][i] = px;
            float sc = ssi[w][c] + sj[c * N_NODES + s];
            sc = sc > 0.f ? sc : 0.2f * sc;
            float e = __expf(sc);
            ex[ii] = e; cc[ii] = c; ww[ii] = __uint_as_float((unsigned)(rv >> 32));
            atomicAdd(&sden[w][c], e);
            atomicAdd(&scnt[w][c], 1);
        }
    }
    #pragma unroll
    for (int ii = 0; ii < 2; ++ii) {
        int i = lane + ii * 64;
        if (i < n)
            ecoef[w][i] = ex[ii] / fmaxf(sden[w][cc[ii]], 1e-16f)
                          * ww[ii] / (float)scnt[w][cc[ii]];
    }
    __syncthreads();                               // rsh cooperative load
    const int sub = lane >> 4, cd = lane & 15;
    float acc = 0.f, acc2 = 0.f;
    int i = sub;
    for (; i + 4 < n; i += 8) {                    // 2-way unrolled strided gather
        int p0 = esrc[w][i], p1 = esrc[w][i + 4];
        int r0 = (p0 >> 16) * N_NODES + (p0 & 0xffff);
        int r1 = (p1 >> 16) * N_NODES + (p1 & 0xffff);
        acc  += ecoef[w][i]     * bf2f(xr2b[(size_t)r0 * 16 + cd]);
        acc2 += ecoef[w][i + 4] * bf2f(xr2b[(size_t)r1 * 16 + cd]);
    }
    if (i < n) {
        int p = esrc[w][i];
        int row = (p >> 16) * N_NODES + (p & 0xffff);
        acc += ecoef[w][i] * bf2f(xr2b[(size_t)row * 16 + cd]);
    }
    acc += acc2;
    #pragma unroll
    for (int k0 = 0; k0 < 16; ++k0) {              // root2 contribution
        int k = sub * 16 + k0;
        acc += hsh[w][k] * rsh[k][cd];
    }
    acc += __shfl_xor(acc, 16, 64);
    acc += __shfl_xor(acc, 32, 64);
    if (sub == 0) {
        acc += bias2[cd];
        float m = acc;
        #pragma unroll
        for (int off = 8; off; off >>= 1) m = fmaxf(m, __shfl_xor(m, off, 16));
        float ex2 = expf(acc - m);
        float ssum = ex2;
        #pragma unroll
        for (int off = 8; off; off >>= 1) ssum += __shfl_xor(ssum, off, 16);
        out[(size_t)d * 16 + cd] = acc - m - logf(ssum);
    }
}

extern "C" void kernel_launch(void* const* d_in, const int* in_sizes, int n_in,
                              void* d_out, int out_size, void* d_ws, size_t ws_size,
                              hipStream_t stream) {
    const float* x     = (const float*)d_in[0];
    const int*   ei    = (const int*)  d_in[1];
    const float* ew    = (const float*)d_in[2];
    const int*   ecol  = (const int*)  d_in[3];
    const float* W1    = (const float*)d_in[4];
    const float* at1   = (const float*)d_in[5];
    const float* root1 = (const float*)d_in[6];
    const float* b1    = (const float*)d_in[7];
    const float* W2    = (const float*)d_in[8];
    const float* at2   = (const float*)d_in[9];
    const float* root2 = (const float*)d_in[10];
    const float* b2    = (const float*)d_in[11];
    float* out = (float*)d_out;
    float* ws  = (float*)d_ws;

    // workspace layout (float offsets)
    ushort*   xb    = (ushort*)(ws + 0);           // 12.8M bf16
    ushort*   wt1   = (ushort*)(ws + 6400000);     // 147,456 bf16 [9][64][256]
    ushort*   xr1b  = (ushort*)(ws + 6480000);     // 25.6M bf16 [R,N,64]
    float*    hroot = ws + 19280000;               // 3.2M
    ushort*   xr2b  = (ushort*)(ws + 22480000);    // 6.4M bf16 [R,N,16]
    float*    si1   = ws + 25680000;               // 400k
    float*    sj1   = ws + 26080000;               // 400k
    float*    si2   = ws + 26480000;               // 400k
    float*    sj2   = ws + 26880000;               // 400k
    int*      fill  = (int*)(ws + 27280000);       // 50k, zeroed
    float*    h     = ws + 27330000;               // 3.2M
    unsigned long long* rec = (unsigned long long*)(ws + 30530000); // 4,800,001 u64

    hipMemsetAsync(fill, 0, (size_t)N_NODES * 4, stream);

    cvt_x_kernel<<<12500, 256, 0, stream>>>(x, xb);
    cvt_w_kernel<<<576, 256, 0, stream>>>(W1, root1, wt1);
    front_kernel<<<FRONT_BLKS, 256, 0, stream>>>(xb, wt1, at1, xr1b, hroot,
                                                 si1, sj1, ei, ecol, ew, fill, rec);
    agg1s_kernel<<<12500, 256, 0, stream>>>(rec, fill, si1, sj1, xr1b, hroot, b1, h);
    proj2_kernel<<<1563, 256, 0, stream>>>(h, W2, at2, xr2b, si2, sj2);
    agg2s_kernel<<<12500, 256, 0, stream>>>(rec, fill, si2, sj2, xr2b, h, root2, b2, out);
}

// Round 6
// 391.851 us; speedup vs baseline: 1.2014x; 1.2014x over previous
//
#include <hip/hip_runtime.h>
#include <math.h>

#define N_NODES 50000
#define N_EDGES 1600000
#define F_IN    256
#define DIMS    64
#define N_CLS   16
#define R_REL   8
#define CAP     96          // per-destination CSR capacity (in-deg ~Poisson(32))

#define PROJ_BLKS 3519      // 391 tiles x 9 "relations" (8 + root slot)
#define CSR_BLKS  3125      // 2 edges/thread: 3125*256*2 == N_EDGES
#define FRONT_BLKS (PROJ_BLKS + CSR_BLKS)   // 6644

typedef short bf16x8 __attribute__((ext_vector_type(8)));
typedef float f32x4  __attribute__((ext_vector_type(4)));
typedef unsigned int u32;
typedef const __attribute__((address_space(1))) u32* gas_ptr;
typedef __attribute__((address_space(3))) u32* las_ptr;

__device__ __forceinline__ void async16(const void* g, void* l) {
    // global->LDS DMA, 16B/lane; LDS dest = uniform base + lane*16
    __builtin_amdgcn_global_load_lds((gas_ptr)g, (las_ptr)l, 16, 0, 0);
}

__device__ __forceinline__ unsigned short f2bf(float f) {
    unsigned u = __float_as_uint(f);
    unsigned r = (u + 0x7fffu + ((u >> 16) & 1u)) >> 16;
    return (unsigned short)r;
}
__device__ __forceinline__ float bf2f(unsigned short u) {
    return __uint_as_float(((unsigned)u) << 16);
}

// ---------- convert x -> bf16 ----------
__global__ __launch_bounds__(256) void cvt_x_kernel(
        const float* __restrict__ x, ushort* __restrict__ xb) {
    int i4 = blockIdx.x * 256 + threadIdx.x;       // 3.2M quads
    float4 v = ((const float4*)x)[i4];
    ushort4 o;
    o.x = f2bf(v.x); o.y = f2bf(v.y); o.z = f2bf(v.z); o.w = f2bf(v.w);
    ((ushort4*)xb)[i4] = o;
}

// ---------- build wt1[r][n][k] bf16 (transposed, slot 8 = root1) ----------
__global__ __launch_bounds__(256) void cvt_w_kernel(
        const float* __restrict__ W1, const float* __restrict__ root1,
        ushort* __restrict__ wt1) {
    int idx = blockIdx.x * 256 + threadIdx.x;      // 9*64*256 = 147456
    int r = idx >> 14, rem = idx & 16383;
    int n = rem >> 8, k = rem & 255;
    float v = (r < 8) ? W1[((size_t)r * F_IN + k) * DIMS + n]
                      : root1[(size_t)k * DIMS + n];
    wt1[idx] = f2bf(v);
}

// ---------- fused front: proj1 MFMA (+si/sj, +x@root1) AND CSR build ----------
// LOCKED round-3 structure: BM=128, 1 relation/block (consecutive blocks
// share one 32KB wt1 slab -> L1-resident B), 3519 proj + 3125 CSR blocks
// interleaved; CSR = 2 edges/thread independent atomic->store chains.
// R1/R2/R5 all proved restructuring proj to cut the 9x staging loses more
// (L1 thrash / wave-count loss) than the fetch saves. Do not touch.
#define BM 128
__global__ __launch_bounds__(256, 6) void front_kernel(
        const ushort* __restrict__ xb, const ushort* __restrict__ wt1,
        const float* __restrict__ at1,
        ushort* __restrict__ xr1b, float* __restrict__ hroot,
        float* __restrict__ si1, float* __restrict__ sj1,
        const int* __restrict__ ei, const int* __restrict__ ecol,
        const float* __restrict__ ew, int* __restrict__ fill,
        unsigned long long* __restrict__ rec) {
    __shared__ ushort xs[BM * 64];                 // 16 KB, swizzled [row][k8^(row&7)]
    const int bid = blockIdx.x;
    const int t = threadIdx.x;

    // interleave: proj/CSR alternate for the first 2*CSR_BLKS bids, then
    // the remaining proj blocks (keeps scatter overlapped with MFMA work)
    int pb = -1, cb = -1;
    if (bid < 2 * CSR_BLKS) { if (bid & 1) cb = bid >> 1; else pb = bid >> 1; }
    else pb = CSR_BLKS + (bid - 2 * CSR_BLKS);

    if (cb >= 0) {
        // ----- CSR build branch: 2 edges/thread, independent chains -----
        int idx = cb * 256 + t;                    // edge-pair index
        int2  s2 = ((const int2*)ei)[idx];
        int2  d2 = ((const int2*)(ei + N_EDGES))[idx];
        int2  c2 = ((const int2*)ecol)[idx];
        float2 w2 = ((const float2*)ew)[idx];
        int p0 = atomicAdd(&fill[d2.x], 1);
        int p1 = atomicAdd(&fill[d2.y], 1);
        unsigned long long r0 =
            ((unsigned long long)__float_as_uint(w2.x) << 32)
            | (unsigned)(s2.x | (c2.x << 16));
        unsigned long long r1 =
            ((unsigned long long)__float_as_uint(w2.y) << 32)
            | (unsigned)(s2.y | (c2.y << 16));
        int i0 = (p0 < CAP) ? d2.x * CAP + p0 : N_NODES * CAP;   // overflow dump
        int i1 = (p1 < CAP) ? d2.y * CAP + p1 : N_NODES * CAP;
        __builtin_nontemporal_store(r0, &rec[i0]);
        __builtin_nontemporal_store(r1, &rec[i1]);
        return;
    }

    // ----- proj1 MFMA branch -----
    const int r = pb / 391;
    const int node0 = (pb % 391) * BM;
    const ushort* wrow = wt1 + (size_t)r * 64 * 256;   // [n][k], L1/L2-resident

    const int w = t >> 6, lane = t & 63;
    const int lane15 = lane & 15, quad = lane >> 4;
    const int row0 = w * 32 + lane15;
    const int sw0 = row0 & 7;

    f32x4 acc[2][4];
    #pragma unroll
    for (int a = 0; a < 2; ++a)
        #pragma unroll
        for (int b = 0; b < 4; ++b)
            acc[a][b] = (f32x4){0.f, 0.f, 0.f, 0.f};

    for (int s = 0; s < 4; ++s) {                  // K staged 4 x 64
        __syncthreads();
        #pragma unroll
        for (int c = 0; c < 4; ++c) {              // 4 x 1024 lane-slots of 16B
            int slot = c * 256 + t;
            int row = slot >> 3, k8p = slot & 7;
            int k8 = k8p ^ (row & 7);              // source-side swizzle
            int node = node0 + row;
            if (node >= N_NODES) node = N_NODES - 1;   // clamp (garbage ok, rows discarded)
            async16(&xb[(size_t)node * 256 + s * 64 + k8 * 8],
                    &xs[(c * 256 + w * 64) * 8]);
        }
        __syncthreads();                           // drains vmcnt incl. lds-DMA
        #pragma unroll
        for (int kk = 0; kk < 2; ++kk) {
            int k8 = kk * 4 + quad;
            int aidx = row0 * 64 + ((k8 ^ sw0) << 3);
            bf16x8 a0 = *(const bf16x8*)&xs[aidx];
            bf16x8 a1 = *(const bf16x8*)&xs[aidx + 16 * 64];
            int kg = s * 64 + kk * 32 + quad * 8;
            #pragma unroll
            for (int nt = 0; nt < 4; ++nt) {
                bf16x8 b = *(const bf16x8*)&wrow[(size_t)(nt * 16 + lane15) * 256 + kg];
                acc[0][nt] = __builtin_amdgcn_mfma_f32_16x16x32_bf16(a0, b, acc[0][nt], 0, 0, 0);
                acc[1][nt] = __builtin_amdgcn_mfma_f32_16x16x32_bf16(a1, b, acc[1][nt], 0, 0, 0);
            }
        }
    }

    const float* at = at1 + r * 128;
    #pragma unroll
    for (int mt = 0; mt < 2; ++mt) {
        float pi[4] = {0.f, 0.f, 0.f, 0.f};
        float pj[4] = {0.f, 0.f, 0.f, 0.f};
        #pragma unroll
        for (int nt = 0; nt < 4; ++nt) {
            int gcol = nt * 16 + lane15;
            float ai = 0.f, aj = 0.f;
            if (r < 8) { ai = at[gcol]; aj = at[64 + gcol]; }
            #pragma unroll
            for (int reg = 0; reg < 4; ++reg) {
                float v = acc[mt][nt][reg];
                int grow = node0 + w * 32 + mt * 16 + quad * 4 + reg;
                if (grow < N_NODES) {
                    if (r < 8)
                        xr1b[((size_t)r * N_NODES + grow) * 64 + gcol] = f2bf(v);
                    else
                        hroot[(size_t)grow * 64 + gcol] = v;
                }
                pi[reg] += ai * v;
                pj[reg] += aj * v;
            }
        }
        if (r < 8) {
            #pragma unroll
            for (int reg = 0; reg < 4; ++reg) {
                float s_ = pi[reg], u_ = pj[reg];
                #pragma unroll
                for (int off = 1; off < 16; off <<= 1) {
                    s_ += __shfl_xor(s_, off, 64);
                    u_ += __shfl_xor(u_, off, 64);
                }
                if (lane15 == 0) {
                    int grow = node0 + w * 32 + mt * 16 + quad * 4 + reg;
                    if (grow < N_NODES) {
                        si1[r * N_NODES + grow] = s_;
                        sj1[r * N_NODES + grow] = u_;
                    }
                }
            }
        }
    }
}

// ---------- layer 1: fused score + aggregate + finalize ----------
// v7: phase-2 gather restructured as half-wave row-pair loads: each lane
// loads 2 adjacent bf16 dims (uint), so one load instruction fetches TWO
// edge rows (2 subs x 32 lanes x 4B = 2 x 128B). 8 chains -> 16 rows in
// flight per wave (was 8) on the latency-bound L3 gather.
__global__ __launch_bounds__(256) void agg1s_kernel(
        const unsigned long long* __restrict__ rec, const int* __restrict__ fill,
        const float* __restrict__ si, const float* __restrict__ sj,
        const ushort* __restrict__ xr1b, const float* __restrict__ hroot,
        const float* __restrict__ bias1, float* __restrict__ h) {
    __shared__ int   esrc[4][CAP];
    __shared__ float ecoef[4][CAP];
    __shared__ float sden[4][8];
    __shared__ int   scnt[4][8];
    __shared__ float ssi[4][8];
    const int t = threadIdx.x;
    const int w = t >> 6, lane = t & 63;
    const int d = blockIdx.x * 4 + w;              // 12500*4 == N_NODES
    if (lane < 8) {
        sden[w][lane] = 0.f; scnt[w][lane] = 0;
        ssi[w][lane] = si[lane * N_NODES + d];
    }
    const int n = min(fill[d], CAP);
    const int base = d * CAP;
    float ex[2] = {0.f, 0.f}, ww[2] = {0.f, 0.f};
    int cc[2] = {0, 0};
    #pragma unroll
    for (int ii = 0; ii < 2; ++ii) {
        int i = lane + ii * 64;
        if (i < n) {
            unsigned long long rv = rec[base + i];
            int px = (int)(unsigned)rv;
            int s = px & 0xffff, c = (px >> 16) & 0x7fff;
            esrc[w][i] = px;
            float sc = ssi[w][c] + sj[c * N_NODES + s];
            sc = sc > 0.f ? sc : 0.2f * sc;
            float e = __expf(sc);
            ex[ii] = e; cc[ii] = c; ww[ii] = __uint_as_float((unsigned)(rv >> 32));
            atomicAdd(&sden[w][c], e);
            atomicAdd(&scnt[w][c], 1);
        }
    }
    #pragma unroll
    for (int ii = 0; ii < 2; ++ii) {
        int i = lane + ii * 64;
        if (i < n)
            ecoef[w][i] = ex[ii] / fmaxf(sden[w][cc[ii]], 1e-16f)
                          * ww[ii] / (float)scnt[w][cc[ii]];
    }
    // phase 2: half-wave row-pair gather, 16 rows in flight per wave
    const int sub = lane >> 5;                     // 0/1: edge parity
    const int l31 = lane & 31;                     // dim pair: 2*l31, 2*l31+1
    float ax[8] = {0.f,0.f,0.f,0.f,0.f,0.f,0.f,0.f};
    float ay[8] = {0.f,0.f,0.f,0.f,0.f,0.f,0.f,0.f};
    int i0 = 0;
    for (; i0 + 16 <= n; i0 += 16) {
        u32 rv[8]; float cf[8];
        #pragma unroll
        for (int u = 0; u < 8; ++u) {
            int e = i0 + 2 * u + sub;
            int p = esrc[w][e];
            cf[u] = ecoef[w][e];
            int row = (p >> 16) * N_NODES + (p & 0xffff);
            rv[u] = *(const u32*)&xr1b[(size_t)row * 64 + 2 * l31];
        }
        #pragma unroll
        for (int u = 0; u < 8; ++u) {
            ax[u] += cf[u] * bf2f((unsigned short)(rv[u] & 0xffffu));
            ay[u] += cf[u] * bf2f((unsigned short)(rv[u] >> 16));
        }
    }
    for (int e = i0 + sub; e < n; e += 2) {        // tail, 2 rows/instr
        int p = esrc[w][e];
        float c = ecoef[w][e];
        int row = (p >> 16) * N_NODES + (p & 0xffff);
        u32 v = *(const u32*)&xr1b[(size_t)row * 64 + 2 * l31];
        ax[0] += c * bf2f((unsigned short)(v & 0xffffu));
        ay[0] += c * bf2f((unsigned short)(v >> 16));
    }
    float sx = ((ax[0] + ax[1]) + (ax[2] + ax[3])) + ((ax[4] + ax[5]) + (ax[6] + ax[7]));
    float sy = ((ay[0] + ay[1]) + (ay[2] + ay[3])) + ((ay[4] + ay[5]) + (ay[6] + ay[7]));
    sx += __shfl_xor(sx, 32, 64);                  // combine edge parities
    sy += __shfl_xor(sy, 32, 64);
    if (sub == 0) {
        float2 hr = *(const float2*)&hroot[(size_t)d * 64 + 2 * l31];
        float2 bi = *(const float2*)&bias1[2 * l31];
        float2 o;
        o.x = fmaxf(sx + hr.x + bi.x, 0.f);
        o.y = fmaxf(sy + hr.y + bi.y, 0.f);
        *(float2*)&h[(size_t)d * 64 + 2 * l31] = o;
    }
}

// ---------- layer 2 projection + si2/sj2 fused (bf16 xr2 out) ----------
__global__ __launch_bounds__(256) void proj2_kernel(
        const float* __restrict__ h, const float* __restrict__ W2,
        const float* __restrict__ atten2, ushort* __restrict__ xr2b,
        float* __restrict__ si2, float* __restrict__ sj2) {
    __shared__ float w2sh[8][64][16];   // 32 KB, [r][k][c]
    __shared__ float a2sh[8][32];
    __shared__ float hsh[32][65];
    const int t = threadIdx.x;
    for (int i = t; i < R_REL * DIMS * N_CLS; i += 256)
        w2sh[i >> 10][(i >> 4) & 63][i & 15] = W2[i];
    if (t < R_REL * 2 * N_CLS) a2sh[t >> 5][t & 31] = atten2[t];
    const int node0 = blockIdx.x * 32;
    for (int i = t; i < 32 * 64; i += 256) {
        int nn = i >> 6, kk = i & 63;
        int node = node0 + nn;
        hsh[nn][kk] = (node < N_NODES) ? h[(size_t)node * 64 + kk] : 0.f;
    }
    __syncthreads();
    const int nl = t & 31, r = t >> 5;
    const int node = node0 + nl;
    float acc[16] = {};
    #pragma unroll 4
    for (int k = 0; k < 64; ++k) {
        float hv = hsh[nl][k];
        #pragma unroll
        for (int c = 0; c < 16; ++c) acc[c] += hv * w2sh[r][k][c];
    }
    if (node < N_NODES) {
        float si = 0.f, sj = 0.f;
        size_t base = ((size_t)r * N_NODES + node) * 16;
        #pragma unroll
        for (int c = 0; c < 16; ++c) {
            si += a2sh[r][c] * acc[c];
            sj += a2sh[r][16 + c] * acc[c];
        }
        #pragma unroll
        for (int c4 = 0; c4 < 4; ++c4) {
            ushort4 o;
            o.x = f2bf(acc[c4 * 4 + 0]); o.y = f2bf(acc[c4 * 4 + 1]);
            o.z = f2bf(acc[c4 * 4 + 2]); o.w = f2bf(acc[c4 * 4 + 3]);
            *(ushort4*)&xr2b[base + c4 * 4] = o;
        }
        si2[r * N_NODES + node] = si;
        sj2[r * N_NODES + node] = sj;
    }
}

// ---------- layer 2: fused score + aggregate + root2 + log_softmax ----------
// v7: gather 4-way unrolled (4 subs x 4 chains = 16 rows in flight).
__global__ __launch_bounds__(256) void agg2s_kernel(
        const unsigned long long* __restrict__ rec, const int* __restrict__ fill,
        const float* __restrict__ si, const float* __restrict__ sj,
        const ushort* __restrict__ xr2b, const float* __restrict__ h,
        const float* __restrict__ root2, const float* __restrict__ bias2,
        float* __restrict__ out) {
    __shared__ float rsh[64][17];
    __shared__ float hsh[4][64];
    __shared__ int   esrc[4][CAP];
    __shared__ float ecoef[4][CAP];
    __shared__ float sden[4][8];
    __shared__ int   scnt[4][8];
    __shared__ float ssi[4][8];
    const int t = threadIdx.x;
    for (int i = t; i < DIMS * N_CLS; i += 256) rsh[i >> 4][i & 15] = root2[i];
    const int w = t >> 6, lane = t & 63;
    const int d = blockIdx.x * 4 + w;
    hsh[w][lane] = h[(size_t)d * 64 + lane];
    if (lane < 8) {
        sden[w][lane] = 0.f; scnt[w][lane] = 0;
        ssi[w][lane] = si[lane * N_NODES + d];
    }
    const int n = min(fill[d], CAP);
    const int base = d * CAP;
    float ex[2] = {0.f, 0.f}, ww[2] = {0.f, 0.f};
    int cc[2] = {0, 0};
    #pragma unroll
    for (int ii = 0; ii < 2; ++ii) {
        int i = lane + ii * 64;
        if (i < n) {
            unsigned long long rv = rec[base + i];
            int px = (int)(unsigned)rv;
            int s = px & 0xffff, c = (px >> 16) & 0x7fff;
            esrc[w][i] = px;
            float sc = ssi[w][c] + sj[c * N_NODES + s];
            sc = sc > 0.f ? sc : 0.2f * sc;
            float e = __expf(sc);
            ex[ii] = e; cc[ii] = c; ww[ii] = __uint_as_float((unsigned)(rv >> 32));
            atomicAdd(&sden[w][c], e);
            atomicAdd(&scnt[w][c], 1);
        }
    }
    #pragma unroll
    for (int ii = 0; ii < 2; ++ii) {
        int i = lane + ii * 64;
        if (i < n)
            ecoef[w][i] = ex[ii] / fmaxf(sden[w][cc[ii]], 1e-16f)
                          * ww[ii] / (float)scnt[w][cc[ii]];
    }
    __syncthreads();                               // rsh cooperative load
    const int sub = lane >> 4, cd = lane & 15;
    float a0 = 0.f, a1 = 0.f, a2 = 0.f, a3 = 0.f;
    int i = sub;
    for (; i + 12 < n; i += 16) {                  // 4-way unrolled strided gather
        int p0 = esrc[w][i],      p1 = esrc[w][i + 4];
        int p2 = esrc[w][i + 8],  p3 = esrc[w][i + 12];
        float c0 = ecoef[w][i],      c1 = ecoef[w][i + 4];
        float c2 = ecoef[w][i + 8],  c3 = ecoef[w][i + 12];
        int r0 = (p0 >> 16) * N_NODES + (p0 & 0xffff);
        int r1 = (p1 >> 16) * N_NODES + (p1 & 0xffff);
        int r2 = (p2 >> 16) * N_NODES + (p2 & 0xffff);
        int r3 = (p3 >> 16) * N_NODES + (p3 & 0xffff);
        a0 += c0 * bf2f(xr2b[(size_t)r0 * 16 + cd]);
        a1 += c1 * bf2f(xr2b[(size_t)r1 * 16 + cd]);
        a2 += c2 * bf2f(xr2b[(size_t)r2 * 16 + cd]);
        a3 += c3 * bf2f(xr2b[(size_t)r3 * 16 + cd]);
    }
    for (; i < n; i += 4) {
        int p = esrc[w][i];
        int row = (p >> 16) * N_NODES + (p & 0xffff);
        a0 += ecoef[w][i] * bf2f(xr2b[(size_t)row * 16 + cd]);
    }
    float acc = (a0 + a1) + (a2 + a3);
    #pragma unroll
    for (int k0 = 0; k0 < 16; ++k0) {              // root2 contribution
        int k = sub * 16 + k0;
        acc += hsh[w][k] * rsh[k][cd];
    }
    acc += __shfl_xor(acc, 16, 64);
    acc += __shfl_xor(acc, 32, 64);
    if (sub == 0) {
        acc += bias2[cd];
        float m = acc;
        #pragma unroll
        for (int off = 8; off; off >>= 1) m = fmaxf(m, __shfl_xor(m, off, 16));
        float ex2 = expf(acc - m);
        float ssum = ex2;
        #pragma unroll
        for (int off = 8; off; off >>= 1) ssum += __shfl_xor(ssum, off, 16);
        out[(size_t)d * 16 + cd] = acc - m - logf(ssum);
    }
}

extern "C" void kernel_launch(void* const* d_in, const int* in_sizes, int n_in,
                              void* d_out, int out_size, void* d_ws, size_t ws_size,
                              hipStream_t stream) {
    const float* x     = (const float*)d_in[0];
    const int*   ei    = (const int*)  d_in[1];
    const float* ew    = (const float*)d_in[2];
    const int*   ecol  = (const int*)  d_in[3];
    const float* W1    = (const float*)d_in[4];
    const float* at1   = (const float*)d_in[5];
    const float* root1 = (const float*)d_in[6];
    const float* b1    = (const float*)d_in[7];
    const float* W2    = (const float*)d_in[8];
    const float* at2   = (const float*)d_in[9];
    const float* root2 = (const float*)d_in[10];
    const float* b2    = (const float*)d_in[11];
    float* out = (float*)d_out;
    float* ws  = (float*)d_ws;

    // workspace layout (float offsets)
    ushort*   xb    = (ushort*)(ws + 0);           // 12.8M bf16
    ushort*   wt1   = (ushort*)(ws + 6400000);     // 147,456 bf16 [9][64][256]
    ushort*   xr1b  = (ushort*)(ws + 6480000);     // 25.6M bf16 [R,N,64]
    float*    hroot = ws + 19280000;               // 3.2M
    ushort*   xr2b  = (ushort*)(ws + 22480000);    // 6.4M bf16 [R,N,16]
    float*    si1   = ws + 25680000;               // 400k
    float*    sj1   = ws + 26080000;               // 400k
    float*    si2   = ws + 26480000;               // 400k
    float*    sj2   = ws + 26880000;               // 400k
    int*      fill  = (int*)(ws + 27280000);       // 50k, zeroed
    float*    h     = ws + 27330000;               // 3.2M
    unsigned long long* rec = (unsigned long long*)(ws + 30530000); // 4,800,001 u64

    hipMemsetAsync(fill, 0, (size_t)N_NODES * 4, stream);

    cvt_x_kernel<<<12500, 256, 0, stream>>>(x, xb);
    cvt_w_kernel<<<576, 256, 0, stream>>>(W1, root1, wt1);
    front_kernel<<<FRONT_BLKS, 256, 0, stream>>>(xb, wt1, at1, xr1b, hroot,
                                                 si1, sj1, ei, ecol, ew, fill, rec);
    agg1s_kernel<<<12500, 256, 0, stream>>>(rec, fill, si1, sj1, xr1b, hroot, b1, h);
    proj2_kernel<<<1563, 256, 0, stream>>>(h, W2, at2, xr2b, si2, sj2);
    agg2s_kernel<<<12500, 256, 0, stream>>>(rec, fill, si2, sj2, xr2b, h, root2, b2, out);
}